// Round 1
// baseline (5078.920 us; speedup 1.0000x reference)
//
#include <hip/hip_runtime.h>

// VGAE encoder forward, all f32.
// Stages:
//   K1  XW1 = X @ W1            [N,512]x[512,16] -> ws.XW1
//   K2  A1  = G @ XW1           edge-parallel atomic scatter
//   K3  M23 = [relu(A1)@W2 | relu(A1)@W3]  -> ws.M23 (stride 16, slots 14/15 pad)
//   K4  A23 = G @ M23           edge-parallel atomic scatter (14 comps)
//   K5  out = A23[:, :7] + eps * exp(A23[:, 7:14])

__global__ void k_xw1(const float* __restrict__ X, const float* __restrict__ W1,
                      float* __restrict__ out, int N) {
    const int lane = threadIdx.x & 63;
    const int ks   = lane >> 2;   // 0..15 : owns k in [ks*32, ks*32+32)
    const int hg   = lane & 3;    // 0..3  : owns h in [hg*4, hg*4+4)
    const int wave  = (blockIdx.x * blockDim.x + threadIdx.x) >> 6;
    const int nwave = (gridDim.x * blockDim.x) >> 6;

    // Per-lane W1 fragment in registers: w[t][i] = W1[ks*32+t][hg*4+i]
    float w[32][4];
#pragma unroll
    for (int t = 0; t < 32; ++t) {
        float4 wv = *reinterpret_cast<const float4*>(W1 + (ks * 32 + t) * 16 + hg * 4);
        w[t][0] = wv.x; w[t][1] = wv.y; w[t][2] = wv.z; w[t][3] = wv.w;
    }

    for (int row = wave; row < N; row += nwave) {
        const float4* xr = reinterpret_cast<const float4*>(X + (size_t)row * 512 + ks * 32);
        float a0 = 0.f, a1 = 0.f, a2 = 0.f, a3 = 0.f;
#pragma unroll
        for (int q = 0; q < 8; ++q) {
            float4 x = xr[q];
            a0 += x.x * w[q*4+0][0]; a1 += x.x * w[q*4+0][1]; a2 += x.x * w[q*4+0][2]; a3 += x.x * w[q*4+0][3];
            a0 += x.y * w[q*4+1][0]; a1 += x.y * w[q*4+1][1]; a2 += x.y * w[q*4+1][2]; a3 += x.y * w[q*4+1][3];
            a0 += x.z * w[q*4+2][0]; a1 += x.z * w[q*4+2][1]; a2 += x.z * w[q*4+2][2]; a3 += x.z * w[q*4+2][3];
            a0 += x.w * w[q*4+3][0]; a1 += x.w * w[q*4+3][1]; a2 += x.w * w[q*4+3][2]; a3 += x.w * w[q*4+3][3];
        }
        // reduce across the 16 kslices (lane bits 2..5)
#pragma unroll
        for (int m = 4; m < 64; m <<= 1) {
            a0 += __shfl_xor(a0, m);
            a1 += __shfl_xor(a1, m);
            a2 += __shfl_xor(a2, m);
            a3 += __shfl_xor(a3, m);
        }
        if (ks == 0) {
            *reinterpret_cast<float4*>(out + (size_t)row * 16 + hg * 4) =
                make_float4(a0, a1, a2, a3);
        }
    }
}

__global__ void k_spmm16(const int* __restrict__ er, const int* __restrict__ ec,
                         const float* __restrict__ ev, const float* __restrict__ H,
                         float* __restrict__ A, int E) {
    int e = blockIdx.x * blockDim.x + threadIdx.x;
    if (e >= E) return;
    const int   r = er[e];
    const int   c = ec[e];
    const float v = ev[e];
    const float4* h = reinterpret_cast<const float4*>(H + (size_t)c * 16);
    float* a = A + (size_t)r * 16;
#pragma unroll
    for (int q = 0; q < 4; ++q) {
        float4 hv = h[q];
        atomicAdd(a + q * 4 + 0, v * hv.x);
        atomicAdd(a + q * 4 + 1, v * hv.y);
        atomicAdd(a + q * 4 + 2, v * hv.z);
        atomicAdd(a + q * 4 + 3, v * hv.w);
    }
}

__global__ void k_spmm14(const int* __restrict__ er, const int* __restrict__ ec,
                         const float* __restrict__ ev, const float* __restrict__ H,
                         float* __restrict__ A, int E) {
    int e = blockIdx.x * blockDim.x + threadIdx.x;
    if (e >= E) return;
    const int   r = er[e];
    const int   c = ec[e];
    const float v = ev[e];
    const float4* h = reinterpret_cast<const float4*>(H + (size_t)c * 16);
    float* a = A + (size_t)r * 16;
#pragma unroll
    for (int q = 0; q < 3; ++q) {
        float4 hv = h[q];
        atomicAdd(a + q * 4 + 0, v * hv.x);
        atomicAdd(a + q * 4 + 1, v * hv.y);
        atomicAdd(a + q * 4 + 2, v * hv.z);
        atomicAdd(a + q * 4 + 3, v * hv.w);
    }
    float4 hv = h[3];
    atomicAdd(a + 12, v * hv.x);
    atomicAdd(a + 13, v * hv.y);
}

__global__ void k_dense23(const float* __restrict__ A1, const float* __restrict__ W2,
                          const float* __restrict__ W3, float* __restrict__ M, int N) {
    int n = blockIdx.x * blockDim.x + threadIdx.x;
    if (n >= N) return;
    float r[16];
    const float4* a = reinterpret_cast<const float4*>(A1 + (size_t)n * 16);
#pragma unroll
    for (int q = 0; q < 4; ++q) {
        float4 v = a[q];
        r[q*4+0] = fmaxf(v.x, 0.f);
        r[q*4+1] = fmaxf(v.y, 0.f);
        r[q*4+2] = fmaxf(v.z, 0.f);
        r[q*4+3] = fmaxf(v.w, 0.f);
    }
    float o[16];
#pragma unroll
    for (int j = 0; j < 7; ++j) {
        float s2 = 0.f, s3 = 0.f;
#pragma unroll
        for (int k = 0; k < 16; ++k) {
            s2 += r[k] * W2[k * 7 + j];   // uniform addr -> scalar loads
            s3 += r[k] * W3[k * 7 + j];
        }
        o[j]     = s2;
        o[7 + j] = s3;
    }
    o[14] = 0.f; o[15] = 0.f;
    float4* m = reinterpret_cast<float4*>(M + (size_t)n * 16);
    m[0] = make_float4(o[0],  o[1],  o[2],  o[3]);
    m[1] = make_float4(o[4],  o[5],  o[6],  o[7]);
    m[2] = make_float4(o[8],  o[9],  o[10], o[11]);
    m[3] = make_float4(o[12], o[13], o[14], o[15]);
}

__global__ void k_out(const float* __restrict__ A23, const float* __restrict__ eps,
                      float* __restrict__ out, int N) {
    int n = blockIdx.x * blockDim.x + threadIdx.x;
    if (n >= N) return;
    float m[16];
    const float4* a = reinterpret_cast<const float4*>(A23 + (size_t)n * 16);
#pragma unroll
    for (int q = 0; q < 4; ++q) {
        float4 v = a[q];
        m[q*4+0] = v.x; m[q*4+1] = v.y; m[q*4+2] = v.z; m[q*4+3] = v.w;
    }
#pragma unroll
    for (int j = 0; j < 7; ++j) {
        out[(size_t)n * 7 + j] = m[j] + eps[(size_t)n * 7 + j] * __expf(m[7 + j]);
    }
}

extern "C" void kernel_launch(void* const* d_in, const int* in_sizes, int n_in,
                              void* d_out, int out_size, void* d_ws, size_t ws_size,
                              hipStream_t stream) {
    const float* X   = (const float*)d_in[0];
    const int*   er  = (const int*)d_in[1];
    const int*   ec  = (const int*)d_in[2];
    const float* ev  = (const float*)d_in[3];
    const float* W1  = (const float*)d_in[4];
    const float* W2  = (const float*)d_in[5];
    const float* W3  = (const float*)d_in[6];
    const float* eps = (const float*)d_in[7];
    float* out = (float*)d_out;

    const int N = in_sizes[0] / 512;
    const int E = in_sizes[1];

    float* ws  = (float*)d_ws;
    float* XW1 = ws;                      // N*16 floats (reused as M23 after K2)
    float* A1  = ws + (size_t)N * 16;     // N*16
    float* A23 = ws + (size_t)N * 32;     // N*16

    // zero both accumulators (contiguous region)
    hipMemsetAsync(A1, 0, (size_t)N * 32 * sizeof(float), stream);

    k_xw1<<<2048, 256, 0, stream>>>(X, W1, XW1, N);
    k_spmm16<<<(E + 255) / 256, 256, 0, stream>>>(er, ec, ev, XW1, A1, E);
    k_dense23<<<(N + 255) / 256, 256, 0, stream>>>(A1, W2, W3, XW1 /*M23*/, N);
    k_spmm14<<<(E + 255) / 256, 256, 0, stream>>>(er, ec, ev, XW1 /*M23*/, A23, E);
    k_out<<<(N + 255) / 256, 256, 0, stream>>>(A23, eps, out, N);
}

// Round 2
// 715.308 us; speedup vs baseline: 7.1003x; 7.1003x over previous
//
#include <hip/hip_runtime.h>

// VGAE encoder forward, all f32.
// R2: replace edge-parallel atomic-scatter SpMM (96M float atomics, 4.9ms)
// with an on-device CSR build (counting sort: hist + scan + scatter, 6.4M
// atomics) and two pull-style SpMMs (atomic-free, L2-resident gathers).
//
// Stages:
//   memset deg
//   k_hist     deg[r]++ per edge
//   k_scan1/2/3 exclusive prefix sum of deg -> start[]
//   k_scatter  csr[pos] = {col, val}; start[] mutates into end[]
//   k_xw1      XW1 = X @ W1                       [N,512]x[512,16]
//   k_pull     A1  = G @ XW1   (pull, 16 lanes/row, lane=feature)
//   k_dense23  M23 = [relu(A1)@W2 | relu(A1)@W3]  (stride 16, pad 14/15 = 0)
//   k_pull     A23 = G @ M23
//   k_out      out = A23[:,:7] + eps * exp(A23[:,7:14])

__global__ void k_hist(const int* __restrict__ er, int* __restrict__ deg, int E) {
    int e = blockIdx.x * blockDim.x + threadIdx.x;
    if (e < E) atomicAdd(&deg[er[e]], 1);
}

__global__ void k_scan1(const int* __restrict__ deg, int* __restrict__ part, int N) {
    __shared__ int sm[256];
    int base = blockIdx.x * 1024 + threadIdx.x * 4;
    int s = 0;
#pragma unroll
    for (int i = 0; i < 4; ++i) { int idx = base + i; if (idx < N) s += deg[idx]; }
    sm[threadIdx.x] = s; __syncthreads();
    for (int off = 128; off > 0; off >>= 1) {
        if (threadIdx.x < off) sm[threadIdx.x] += sm[threadIdx.x + off];
        __syncthreads();
    }
    if (threadIdx.x == 0) part[blockIdx.x] = sm[0];
}

__global__ void k_scan2(int* __restrict__ part, int NB) {
    __shared__ int sm[256];
    int t = threadIdx.x;
    if (t < NB) sm[t] = part[t];
    __syncthreads();
    if (t == 0) {
        int run = 0;
        for (int i = 0; i < NB; ++i) { int v = sm[i]; sm[i] = run; run += v; }
    }
    __syncthreads();
    if (t < NB) part[t] = sm[t];
}

__global__ void k_scan3(const int* __restrict__ deg, const int* __restrict__ part,
                        int* __restrict__ start, int N) {
    __shared__ int sm[256];
    int t = threadIdx.x;
    int base = blockIdx.x * 1024 + t * 4;
    int v[4]; int s = 0;
#pragma unroll
    for (int i = 0; i < 4; ++i) { int idx = base + i; v[i] = (idx < N) ? deg[idx] : 0; s += v[i]; }
    sm[t] = s; __syncthreads();
    for (int off = 1; off < 256; off <<= 1) {
        int x = (t >= off) ? sm[t - off] : 0;
        __syncthreads();
        sm[t] += x;
        __syncthreads();
    }
    int excl = sm[t] - s + part[blockIdx.x];
#pragma unroll
    for (int i = 0; i < 4; ++i) {
        int idx = base + i;
        if (idx < N) { start[idx] = excl; excl += v[i]; }
    }
}

__global__ void k_scatter(const int* __restrict__ er, const int* __restrict__ ec,
                          const float* __restrict__ ev, int* __restrict__ cursor,
                          uint2* __restrict__ csr, int E) {
    int e = blockIdx.x * blockDim.x + threadIdx.x;
    if (e >= E) return;
    int r = er[e];
    int pos = atomicAdd(&cursor[r], 1);
    csr[pos] = make_uint2((unsigned)ec[e], __float_as_uint(ev[e]));
}

__global__ void k_xw1(const float* __restrict__ X, const float* __restrict__ W1,
                      float* __restrict__ out, int N) {
    const int lane = threadIdx.x & 63;
    const int ks   = lane >> 2;   // 0..15 : owns k in [ks*32, ks*32+32)
    const int hg   = lane & 3;    // 0..3  : owns h in [hg*4, hg*4+4)
    const int wave  = (blockIdx.x * blockDim.x + threadIdx.x) >> 6;
    const int nwave = (gridDim.x * blockDim.x) >> 6;

    float w[32][4];
#pragma unroll
    for (int t = 0; t < 32; ++t) {
        float4 wv = *reinterpret_cast<const float4*>(W1 + (ks * 32 + t) * 16 + hg * 4);
        w[t][0] = wv.x; w[t][1] = wv.y; w[t][2] = wv.z; w[t][3] = wv.w;
    }

    for (int row = wave; row < N; row += nwave) {
        const float4* xr = reinterpret_cast<const float4*>(X + (size_t)row * 512 + ks * 32);
        float a0 = 0.f, a1 = 0.f, a2 = 0.f, a3 = 0.f;
#pragma unroll
        for (int q = 0; q < 8; ++q) {
            float4 x = xr[q];
            a0 += x.x * w[q*4+0][0]; a1 += x.x * w[q*4+0][1]; a2 += x.x * w[q*4+0][2]; a3 += x.x * w[q*4+0][3];
            a0 += x.y * w[q*4+1][0]; a1 += x.y * w[q*4+1][1]; a2 += x.y * w[q*4+1][2]; a3 += x.y * w[q*4+1][3];
            a0 += x.z * w[q*4+2][0]; a1 += x.z * w[q*4+2][1]; a2 += x.z * w[q*4+2][2]; a3 += x.z * w[q*4+2][3];
            a0 += x.w * w[q*4+3][0]; a1 += x.w * w[q*4+3][1]; a2 += x.w * w[q*4+3][2]; a3 += x.w * w[q*4+3][3];
        }
#pragma unroll
        for (int m = 4; m < 64; m <<= 1) {
            a0 += __shfl_xor(a0, m);
            a1 += __shfl_xor(a1, m);
            a2 += __shfl_xor(a2, m);
            a3 += __shfl_xor(a3, m);
        }
        if (ks == 0) {
            *reinterpret_cast<float4*>(out + (size_t)row * 16 + hg * 4) =
                make_float4(a0, a1, a2, a3);
        }
    }
}

// Pull SpMM: 16 lanes per row, lane = feature index. csr/end/deg reads are
// uniform across the 16-lane group (cache-broadcast); H gathers are 64B
// coalesced per group and land in L2 (feature table = 6.4 MB).
__global__ void k_pull(const uint2* __restrict__ csr, const int* __restrict__ endp,
                       const int* __restrict__ deg, const float* __restrict__ H,
                       float* __restrict__ A, int N) {
    int t = blockIdx.x * blockDim.x + threadIdx.x;
    int row = t >> 4;
    int f   = t & 15;
    if (row >= N) return;
    int end = endp[row];
    int beg = end - deg[row];
    float acc = 0.f;
    for (int j = beg; j < end; ++j) {
        uint2 cv = csr[j];
        acc += __uint_as_float(cv.y) * H[(size_t)cv.x * 16 + f];
    }
    A[(size_t)row * 16 + f] = acc;
}

__global__ void k_dense23(const float* __restrict__ A1, const float* __restrict__ W2,
                          const float* __restrict__ W3, float* __restrict__ M, int N) {
    int n = blockIdx.x * blockDim.x + threadIdx.x;
    if (n >= N) return;
    float r[16];
    const float4* a = reinterpret_cast<const float4*>(A1 + (size_t)n * 16);
#pragma unroll
    for (int q = 0; q < 4; ++q) {
        float4 v = a[q];
        r[q*4+0] = fmaxf(v.x, 0.f);
        r[q*4+1] = fmaxf(v.y, 0.f);
        r[q*4+2] = fmaxf(v.z, 0.f);
        r[q*4+3] = fmaxf(v.w, 0.f);
    }
    float o[16];
#pragma unroll
    for (int j = 0; j < 7; ++j) {
        float s2 = 0.f, s3 = 0.f;
#pragma unroll
        for (int k = 0; k < 16; ++k) {
            s2 += r[k] * W2[k * 7 + j];
            s3 += r[k] * W3[k * 7 + j];
        }
        o[j]     = s2;
        o[7 + j] = s3;
    }
    o[14] = 0.f; o[15] = 0.f;
    float4* m = reinterpret_cast<float4*>(M + (size_t)n * 16);
    m[0] = make_float4(o[0],  o[1],  o[2],  o[3]);
    m[1] = make_float4(o[4],  o[5],  o[6],  o[7]);
    m[2] = make_float4(o[8],  o[9],  o[10], o[11]);
    m[3] = make_float4(o[12], o[13], o[14], o[15]);
}

__global__ void k_out(const float* __restrict__ A23, const float* __restrict__ eps,
                      float* __restrict__ out, int N) {
    int n = blockIdx.x * blockDim.x + threadIdx.x;
    if (n >= N) return;
    float m[16];
    const float4* a = reinterpret_cast<const float4*>(A23 + (size_t)n * 16);
#pragma unroll
    for (int q = 0; q < 4; ++q) {
        float4 v = a[q];
        m[q*4+0] = v.x; m[q*4+1] = v.y; m[q*4+2] = v.z; m[q*4+3] = v.w;
    }
#pragma unroll
    for (int j = 0; j < 7; ++j) {
        out[(size_t)n * 7 + j] = m[j] + eps[(size_t)n * 7 + j] * __expf(m[7 + j]);
    }
}

extern "C" void kernel_launch(void* const* d_in, const int* in_sizes, int n_in,
                              void* d_out, int out_size, void* d_ws, size_t ws_size,
                              hipStream_t stream) {
    const float* X   = (const float*)d_in[0];
    const int*   er  = (const int*)d_in[1];
    const int*   ec  = (const int*)d_in[2];
    const float* ev  = (const float*)d_in[3];
    const float* W1  = (const float*)d_in[4];
    const float* W2  = (const float*)d_in[5];
    const float* W3  = (const float*)d_in[6];
    const float* eps = (const float*)d_in[7];
    float* out = (float*)d_out;

    const int N = in_sizes[0] / 512;
    const int E = in_sizes[1];
    const int NB = (N + 1023) / 1024;   // scan blocks (98 for N=100000; must be <=256)

    // workspace layout (floats/ints, 16B-aligned chunks)
    float* ws   = (float*)d_ws;
    float* XW1  = ws;                       // N*16 f32 (reused as M23)
    float* A1   = ws + (size_t)N * 16;      // N*16 f32
    float* A23  = ws + (size_t)N * 32;      // N*16 f32
    int*   deg  = (int*)(ws + (size_t)N * 48);        // N i32
    int*   start= deg + N;                            // N i32 (mutates to end[])
    int*   part = start + N;                          // NB i32 (pad 256)
    uint2* csr  = (uint2*)(part + 256);               // E x 8B

    hipMemsetAsync(deg, 0, (size_t)N * sizeof(int), stream);
    k_hist   <<<(E + 255) / 256, 256, 0, stream>>>(er, deg, E);
    k_scan1  <<<NB, 256, 0, stream>>>(deg, part, N);
    k_scan2  <<<1, 256, 0, stream>>>(part, NB);
    k_scan3  <<<NB, 256, 0, stream>>>(deg, part, start, N);
    k_scatter<<<(E + 255) / 256, 256, 0, stream>>>(er, ec, ev, start, csr, E);

    k_xw1    <<<2048, 256, 0, stream>>>(X, W1, XW1, N);
    k_pull   <<<(N * 16 + 255) / 256, 256, 0, stream>>>(csr, start /*=end*/, deg, XW1, A1, N);
    k_dense23<<<(N + 255) / 256, 256, 0, stream>>>(A1, W2, W3, XW1 /*M23*/, N);
    k_pull   <<<(N * 16 + 255) / 256, 256, 0, stream>>>(csr, start /*=end*/, deg, XW1 /*M23*/, A23, N);
    k_out    <<<(N + 255) / 256, 256, 0, stream>>>(A23, eps, out, N);
}

// Round 3
// 651.485 us; speedup vs baseline: 7.7959x; 1.0980x over previous
//
#include <hip/hip_runtime.h>

// VGAE encoder forward, all f32.
// R3: XCD-aware scatter. R2's k_scatter showed WRITE_SIZE=198MB for a 25.6MB
// csr payload (8x amplification): csr lines were written by threads on all 8
// XCDs, whose non-coherent L2s each evict partial lines. Fix: partition rows
// into 8 contiguous classes; blocks with blockIdx.x%8==k scan ALL edges and
// commit only class-k rows (default block->XCD mapping is round-robin, so
// class k lands on XCD k). csr segment + cursor slice per class become
// XCD-local -> full-line evictions, local atomics. k_pull uses the same row
// mapping so each XCD reads the csr region it just wrote (L2-hot).
//
// Stages:
//   memset deg
//   k_hist      deg[r]++ per edge
//   k_scan1/2/3 exclusive prefix sum of deg -> start[]
//   k_scatter_x csr[pos] = {col, val}; start[] mutates into end[]
//   k_xw1       XW1 = X @ W1                       [N,512]x[512,16]
//   k_pull      A1  = G @ XW1   (pull, 16 lanes/row, lane=feature)
//   k_dense23   M23 = [relu(A1)@W2 | relu(A1)@W3]  (stride 16, pad 14/15 = 0)
//   k_pull      A23 = G @ M23
//   k_out       out = A23[:,:7] + eps * exp(A23[:,7:14])

__global__ void k_hist(const int* __restrict__ er, int* __restrict__ deg, int E) {
    int e = blockIdx.x * blockDim.x + threadIdx.x;
    if (e < E) atomicAdd(&deg[er[e]], 1);
}

__global__ void k_scan1(const int* __restrict__ deg, int* __restrict__ part, int N) {
    __shared__ int sm[256];
    int base = blockIdx.x * 1024 + threadIdx.x * 4;
    int s = 0;
#pragma unroll
    for (int i = 0; i < 4; ++i) { int idx = base + i; if (idx < N) s += deg[idx]; }
    sm[threadIdx.x] = s; __syncthreads();
    for (int off = 128; off > 0; off >>= 1) {
        if (threadIdx.x < off) sm[threadIdx.x] += sm[threadIdx.x + off];
        __syncthreads();
    }
    if (threadIdx.x == 0) part[blockIdx.x] = sm[0];
}

__global__ void k_scan2(int* __restrict__ part, int NB) {
    __shared__ int sm[256];
    int t = threadIdx.x;
    if (t < NB) sm[t] = part[t];
    __syncthreads();
    if (t == 0) {
        int run = 0;
        for (int i = 0; i < NB; ++i) { int v = sm[i]; sm[i] = run; run += v; }
    }
    __syncthreads();
    if (t < NB) part[t] = sm[t];
}

__global__ void k_scan3(const int* __restrict__ deg, const int* __restrict__ part,
                        int* __restrict__ start, int N) {
    __shared__ int sm[256];
    int t = threadIdx.x;
    int base = blockIdx.x * 1024 + t * 4;
    int v[4]; int s = 0;
#pragma unroll
    for (int i = 0; i < 4; ++i) { int idx = base + i; v[i] = (idx < N) ? deg[idx] : 0; s += v[i]; }
    sm[t] = s; __syncthreads();
    for (int off = 1; off < 256; off <<= 1) {
        int x = (t >= off) ? sm[t - off] : 0;
        __syncthreads();
        sm[t] += x;
        __syncthreads();
    }
    int excl = sm[t] - s + part[blockIdx.x];
#pragma unroll
    for (int i = 0; i < 4; ++i) {
        int idx = base + i;
        if (idx < N) { start[idx] = excl; excl += v[i]; }
    }
}

// XCD-partitioned scatter: class vx = blockIdx.x & 7 commits only rows in
// [vx*N8, vx*N8+N8). Every edge is scanned by all 8 classes (reads L3-hit
// after first touch); commits are XCD-local.
__global__ void k_scatter_x(const int* __restrict__ er, const int* __restrict__ ec,
                            const float* __restrict__ ev, int* __restrict__ cursor,
                            uint2* __restrict__ csr, int E, int N8) {
    const int vx = blockIdx.x & 7;
    const int nb = gridDim.x >> 3;
    const int jb = blockIdx.x >> 3;
    const int lo = vx * N8, hi = lo + N8;
    for (int e = jb * blockDim.x + threadIdx.x; e < E; e += nb * blockDim.x) {
        int r = er[e];
        if (r >= lo && r < hi) {
            int pos = atomicAdd(&cursor[r], 1);
            csr[pos] = make_uint2((unsigned)ec[e], __float_as_uint(ev[e]));
        }
    }
}

__global__ void k_xw1(const float* __restrict__ X, const float* __restrict__ W1,
                      float* __restrict__ out, int N) {
    const int lane = threadIdx.x & 63;
    const int ks   = lane >> 2;   // 0..15 : owns k in [ks*32, ks*32+32)
    const int hg   = lane & 3;    // 0..3  : owns h in [hg*4, hg*4+4)
    const int wave  = (blockIdx.x * blockDim.x + threadIdx.x) >> 6;
    const int nwave = (gridDim.x * blockDim.x) >> 6;

    float w[32][4];
#pragma unroll
    for (int t = 0; t < 32; ++t) {
        float4 wv = *reinterpret_cast<const float4*>(W1 + (ks * 32 + t) * 16 + hg * 4);
        w[t][0] = wv.x; w[t][1] = wv.y; w[t][2] = wv.z; w[t][3] = wv.w;
    }

    for (int row = wave; row < N; row += nwave) {
        const float4* xr = reinterpret_cast<const float4*>(X + (size_t)row * 512 + ks * 32);
        float a0 = 0.f, a1 = 0.f, a2 = 0.f, a3 = 0.f;
#pragma unroll
        for (int q = 0; q < 8; ++q) {
            float4 x = xr[q];
            a0 += x.x * w[q*4+0][0]; a1 += x.x * w[q*4+0][1]; a2 += x.x * w[q*4+0][2]; a3 += x.x * w[q*4+0][3];
            a0 += x.y * w[q*4+1][0]; a1 += x.y * w[q*4+1][1]; a2 += x.y * w[q*4+1][2]; a3 += x.y * w[q*4+1][3];
            a0 += x.z * w[q*4+2][0]; a1 += x.z * w[q*4+2][1]; a2 += x.z * w[q*4+2][2]; a3 += x.z * w[q*4+2][3];
            a0 += x.w * w[q*4+3][0]; a1 += x.w * w[q*4+3][1]; a2 += x.w * w[q*4+3][2]; a3 += x.w * w[q*4+3][3];
        }
#pragma unroll
        for (int m = 4; m < 64; m <<= 1) {
            a0 += __shfl_xor(a0, m);
            a1 += __shfl_xor(a1, m);
            a2 += __shfl_xor(a2, m);
            a3 += __shfl_xor(a3, m);
        }
        if (ks == 0) {
            *reinterpret_cast<float4*>(out + (size_t)row * 16 + hg * 4) =
                make_float4(a0, a1, a2, a3);
        }
    }
}

// Pull SpMM, rows mapped with the same %8 class scheme as the scatter so each
// XCD reads the csr region it wrote. 16 lanes per row, lane = feature.
__global__ void k_pull(const uint2* __restrict__ csr, const int* __restrict__ endp,
                       const int* __restrict__ deg, const float* __restrict__ H,
                       float* __restrict__ A, int N, int N8) {
    const int vx = blockIdx.x & 7;
    const int jb = blockIdx.x >> 3;
    int local = jb * (blockDim.x >> 4) + (threadIdx.x >> 4);
    if (local >= N8) return;
    int row = vx * N8 + local;
    if (row >= N) return;
    int f = threadIdx.x & 15;
    int end = endp[row];
    int beg = end - deg[row];
    float acc = 0.f;
    for (int j = beg; j < end; ++j) {
        uint2 cv = csr[j];
        acc += __uint_as_float(cv.y) * H[(size_t)cv.x * 16 + f];
    }
    A[(size_t)row * 16 + f] = acc;
}

__global__ void k_dense23(const float* __restrict__ A1, const float* __restrict__ W2,
                          const float* __restrict__ W3, float* __restrict__ M, int N) {
    int n = blockIdx.x * blockDim.x + threadIdx.x;
    if (n >= N) return;
    float r[16];
    const float4* a = reinterpret_cast<const float4*>(A1 + (size_t)n * 16);
#pragma unroll
    for (int q = 0; q < 4; ++q) {
        float4 v = a[q];
        r[q*4+0] = fmaxf(v.x, 0.f);
        r[q*4+1] = fmaxf(v.y, 0.f);
        r[q*4+2] = fmaxf(v.z, 0.f);
        r[q*4+3] = fmaxf(v.w, 0.f);
    }
    float o[16];
#pragma unroll
    for (int j = 0; j < 7; ++j) {
        float s2 = 0.f, s3 = 0.f;
#pragma unroll
        for (int k = 0; k < 16; ++k) {
            s2 += r[k] * W2[k * 7 + j];
            s3 += r[k] * W3[k * 7 + j];
        }
        o[j]     = s2;
        o[7 + j] = s3;
    }
    o[14] = 0.f; o[15] = 0.f;
    float4* m = reinterpret_cast<float4*>(M + (size_t)n * 16);
    m[0] = make_float4(o[0],  o[1],  o[2],  o[3]);
    m[1] = make_float4(o[4],  o[5],  o[6],  o[7]);
    m[2] = make_float4(o[8],  o[9],  o[10], o[11]);
    m[3] = make_float4(o[12], o[13], o[14], o[15]);
}

__global__ void k_out(const float* __restrict__ A23, const float* __restrict__ eps,
                      float* __restrict__ out, int N) {
    int n = blockIdx.x * blockDim.x + threadIdx.x;
    if (n >= N) return;
    float m[16];
    const float4* a = reinterpret_cast<const float4*>(A23 + (size_t)n * 16);
#pragma unroll
    for (int q = 0; q < 4; ++q) {
        float4 v = a[q];
        m[q*4+0] = v.x; m[q*4+1] = v.y; m[q*4+2] = v.z; m[q*4+3] = v.w;
    }
#pragma unroll
    for (int j = 0; j < 7; ++j) {
        out[(size_t)n * 7 + j] = m[j] + eps[(size_t)n * 7 + j] * __expf(m[7 + j]);
    }
}

extern "C" void kernel_launch(void* const* d_in, const int* in_sizes, int n_in,
                              void* d_out, int out_size, void* d_ws, size_t ws_size,
                              hipStream_t stream) {
    const float* X   = (const float*)d_in[0];
    const int*   er  = (const int*)d_in[1];
    const int*   ec  = (const int*)d_in[2];
    const float* ev  = (const float*)d_in[3];
    const float* W1  = (const float*)d_in[4];
    const float* W2  = (const float*)d_in[5];
    const float* W3  = (const float*)d_in[6];
    const float* eps = (const float*)d_in[7];
    float* out = (float*)d_out;

    const int N  = in_sizes[0] / 512;
    const int E  = in_sizes[1];
    const int NB = (N + 1023) / 1024;   // scan blocks (98; must be <=256)
    const int N8 = (N + 7) / 8;         // rows per XCD class

    // workspace layout
    float* ws   = (float*)d_ws;
    float* XW1  = ws;                       // N*16 f32 (reused as M23)
    float* A1   = ws + (size_t)N * 16;      // N*16 f32
    float* A23  = ws + (size_t)N * 32;      // N*16 f32
    int*   deg  = (int*)(ws + (size_t)N * 48);        // N i32
    int*   start= deg + N;                            // N i32 (mutates to end[])
    int*   part = start + N;                          // NB i32 (pad 256)
    uint2* csr  = (uint2*)(part + 256);               // E x 8B

    hipMemsetAsync(deg, 0, (size_t)N * sizeof(int), stream);
    k_hist   <<<(E + 255) / 256, 256, 0, stream>>>(er, deg, E);
    k_scan1  <<<NB, 256, 0, stream>>>(deg, part, N);
    k_scan2  <<<1, 256, 0, stream>>>(part, NB);
    k_scan3  <<<NB, 256, 0, stream>>>(deg, part, start, N);
    k_scatter_x<<<2048, 256, 0, stream>>>(er, ec, ev, start, csr, E, N8);

    const int pull_grid = 8 * ((N8 + 15) / 16);   // 16 rows/block, 8 classes
    k_xw1    <<<2048, 256, 0, stream>>>(X, W1, XW1, N);
    k_pull   <<<pull_grid, 256, 0, stream>>>(csr, start /*=end*/, deg, XW1, A1, N, N8);
    k_dense23<<<(N + 255) / 256, 256, 0, stream>>>(A1, W2, W3, XW1 /*M23*/, N);
    k_pull   <<<pull_grid, 256, 0, stream>>>(csr, start /*=end*/, deg, XW1 /*M23*/, A23, N, N8);
    k_out    <<<(N + 255) / 256, 256, 0, stream>>>(A23, eps, out, N);
}